// Round 1
// baseline (1226.407 us; speedup 1.0000x reference)
//
#include <hip/hip_runtime.h>
#include <math.h>

#define T_SEQ 4096
#define HID 2048
#define FFN1 1408
#define TWO_FFN 2816
#define NE 8
#define NSLOT 8192   // T_SEQ * TOP_K

typedef unsigned short u16;
typedef __bf16 bf16x8_t __attribute__((ext_vector_type(8)));
typedef float f32x4_t __attribute__((ext_vector_type(4)));

__device__ __forceinline__ u16 f2bf(float f) {
    union { float f; unsigned int u; } v; v.f = f;
    unsigned int u = v.u;
    unsigned int r = u + 0x7FFFu + ((u >> 16) & 1u);
    return (u16)(r >> 16);
}
__device__ __forceinline__ float bf2f(u16 b) {
    union { unsigned int u; float f; } v; v.u = ((unsigned int)b) << 16;
    return v.f;
}
__device__ __forceinline__ unsigned pack2(float a, float b) {
    return (unsigned)f2bf(a) | ((unsigned)f2bf(b) << 16);
}

// ---------------- fp32 -> bf16 bulk convert (8 elems/thread) ----------------
__global__ __launch_bounds__(256) void cvt_kernel(const float* __restrict__ in,
                                                  u16* __restrict__ out, long n) {
    long i = ((long)blockIdx.x * 256 + threadIdx.x) * 8;
    if (i + 8 > n) return;
    const float4* p = (const float4*)(in + i);
    float4 a = p[0], b = p[1];
    uint4 o;
    o.x = pack2(a.x, a.y);
    o.y = pack2(a.z, a.w);
    o.z = pack2(b.x, b.y);
    o.w = pack2(b.z, b.w);
    *(uint4*)(out + i) = o;
}

// ---------------- router: logits, top-2, weights, counts ----------------
__global__ __launch_bounds__(256) void router_kernel(
    const float* __restrict__ x, const float* __restrict__ gw,
    float* __restrict__ logits_out, int* __restrict__ pairs,
    float2* __restrict__ wts, int* __restrict__ counts) {
    int wave = threadIdx.x >> 6, lane = threadIdx.x & 63;
    int t = blockIdx.x * 4 + wave;
    float acc[NE] = {0.f,0.f,0.f,0.f,0.f,0.f,0.f,0.f};
    const float* xr = x + (long)t * HID;
    for (int i = 0; i < HID / 64; ++i) {
        int hh = i * 64 + lane;
        float xv = xr[hh];
        const float4* g4 = (const float4*)(gw + (long)hh * NE);
        float4 g0 = g4[0], g1 = g4[1];
        acc[0] += xv * g0.x; acc[1] += xv * g0.y;
        acc[2] += xv * g0.z; acc[3] += xv * g0.w;
        acc[4] += xv * g1.x; acc[5] += xv * g1.y;
        acc[6] += xv * g1.z; acc[7] += xv * g1.w;
    }
    #pragma unroll
    for (int m = 1; m < 64; m <<= 1) {
        #pragma unroll
        for (int e = 0; e < NE; ++e) acc[e] += __shfl_xor(acc[e], m, 64);
    }
    if (lane == 0) {
        float* lo = logits_out + (long)t * NE;
        #pragma unroll
        for (int e = 0; e < NE; ++e) lo[e] = acc[e];
        int a = 0; float va = acc[0];
        #pragma unroll
        for (int e = 1; e < NE; ++e) if (acc[e] > va) { va = acc[e]; a = e; }
        int b = -1; float vb = 0.f;
        #pragma unroll
        for (int e = 0; e < NE; ++e) {
            if (e == a) continue;
            if (b < 0 || acc[e] > vb) { vb = acc[e]; b = e; }
        }
        float w0 = 1.0f / (1.0f + expf(vb - va));
        pairs[t] = a | (b << 8);
        wts[t] = make_float2(w0, 1.0f - w0);
        atomicAdd(counts + a, 1);
        atomicAdd(counts + b, 1);
    }
}

// ---------------- prefix offsets (E=8, single thread) ----------------
__global__ void offsets_kernel(const int* __restrict__ counts, int* __restrict__ offs) {
    int s = 0;
    for (int e = 0; e < NE; ++e) { offs[e] = s; s += counts[e]; }
    offs[NE] = s;
}

// ---------------- scatter tokens into compact expert segments ----------------
__global__ __launch_bounds__(256) void scatter_kernel(
    const int* __restrict__ pairs, const int* __restrict__ offs,
    int* __restrict__ cursor, int* __restrict__ tok_of, int* __restrict__ inv) {
    int t = blockIdx.x * 256 + threadIdx.x;
    if (t >= T_SEQ) return;
    int pr = pairs[t];
    int a = pr & 0xFF, b = (pr >> 8) & 0xFF;
    int p0 = atomicAdd(cursor + a, 1);
    int s0 = offs[a] + p0;
    tok_of[s0] = t; inv[2 * t] = s0;
    int p1 = atomicAdd(cursor + b, 1);
    int s1 = offs[b] + p1;
    tok_of[s1] = t; inv[2 * t + 1] = s1;
}

// ---------------- gather hidden rows to compact bf16 A ----------------
__global__ __launch_bounds__(256) void gather_kernel(
    const float* __restrict__ x, const int* __restrict__ tok_of, u16* __restrict__ Ab) {
    int slot = blockIdx.x;
    int tok = tok_of[slot];
    int c = threadIdx.x * 8;
    const float4* p = (const float4*)(x + (long)tok * HID + c);
    float4 a = p[0], b = p[1];
    uint4 o;
    o.x = pack2(a.x, a.y);
    o.y = pack2(a.z, a.w);
    o.z = pack2(b.x, b.y);
    o.w = pack2(b.z, b.w);
    *(uint4*)(Ab + (long)slot * HID + c) = o;
}

// ---------------- grouped GEMM, m97 structure ----------------
// A [Mtot, K] bf16 row-major (compact slots); B [E, N, K] bf16 (B^T layout);
// C [Mtot, ldc] bf16. Per expert e rows [offs[e], offs[e+1]).
__device__ __forceinline__ void async16(const u16* g, u16* l) {
    __builtin_amdgcn_global_load_lds(
        (const __attribute__((address_space(1))) void*)g,
        (__attribute__((address_space(3))) void*)l, 16, 0, 0);
}

__global__ __launch_bounds__(256) void gemm_bt(
    const u16* __restrict__ A, const u16* __restrict__ B, u16* __restrict__ C,
    const int* __restrict__ offs, int N, int K, int ldc, int Mtot) {
    int e = blockIdx.z;
    int m_base = offs[e];
    int m_cnt = offs[e + 1] - m_base;
    int m0 = blockIdx.x * 128;
    if (m0 >= m_cnt) return;
    int n0 = blockIdx.y * 128;

    __shared__ u16 As[128 * 32];
    __shared__ u16 Bs[128 * 32];

    int tid = threadIdx.x;
    int lane = tid & 63;
    int wave = tid >> 6;
    const u16* Be = B + (long)e * N * K;

    // staging: 128 rows x 32 cols bf16 = 8KB per tile; 256 thr x 16B = 2 passes
    int rA0 = m_base + m0 + (tid >> 2);
    int rA1 = rA0 + 64;
    if (rA0 > Mtot - 1) rA0 = Mtot - 1;   // clamp: garbage rows masked at store
    if (rA1 > Mtot - 1) rA1 = Mtot - 1;
    int ch = (tid & 3) * 8;
    const u16* gA0 = A + (long)rA0 * K + ch;
    const u16* gA1 = A + (long)rA1 * K + ch;
    const u16* gB0 = Be + (long)(n0 + (tid >> 2)) * K + ch;
    const u16* gB1 = Be + (long)(n0 + 64 + (tid >> 2)) * K + ch;
    u16* lA0 = As + tid * 8;
    u16* lA1 = As + (256 + tid) * 8;
    u16* lB0 = Bs + tid * 8;
    u16* lB1 = Bs + (256 + tid) * 8;

    f32x4_t acc[4][4] = {};
    int wm = (wave >> 1) << 6;
    int wn = (wave & 1) << 6;
    int fr = lane & 15;
    int kg = (lane >> 4) * 8;

    for (int k0 = 0; k0 < K; k0 += 32) {
        __syncthreads();
        async16(gA0 + k0, lA0);
        async16(gA1 + k0, lA1);
        async16(gB0 + k0, lB0);
        async16(gB1 + k0, lB1);
        __syncthreads();
        bf16x8_t av[4], bv[4];
        #pragma unroll
        for (int i = 0; i < 4; ++i)
            av[i] = *(const bf16x8_t*)(As + (wm + i * 16 + fr) * 32 + kg);
        #pragma unroll
        for (int j = 0; j < 4; ++j)
            bv[j] = *(const bf16x8_t*)(Bs + (wn + j * 16 + fr) * 32 + kg);
        #pragma unroll
        for (int i = 0; i < 4; ++i)
            #pragma unroll
            for (int j = 0; j < 4; ++j)
                acc[i][j] = __builtin_amdgcn_mfma_f32_16x16x32_bf16(av[i], bv[j], acc[i][j], 0, 0, 0);
    }

    // epilogue: C/D layout col=lane&15, row=(lane>>4)*4+reg  [m89-verified]
    int cr = (lane >> 4) * 4;
    int cc = lane & 15;
    #pragma unroll
    for (int i = 0; i < 4; ++i) {
        #pragma unroll
        for (int j = 0; j < 4; ++j) {
            int gcol = n0 + wn + j * 16 + cc;
            #pragma unroll
            for (int r = 0; r < 4; ++r) {
                int mr = m0 + wm + i * 16 + cr + r;
                if (mr < m_cnt)
                    C[(long)(m_base + mr) * ldc + gcol] = f2bf(acc[i][j][r]);
            }
        }
    }
}

// ---------------- SiLU gate: act = silu(g) * u ----------------
__global__ __launch_bounds__(256) void act_kernel(const u16* __restrict__ h,
                                                  u16* __restrict__ act) {
    long i = (long)blockIdx.x * 256 + threadIdx.x;   // one per 4 elems
    long s = i / (FFN1 / 4);
    int f = (int)(i % (FFN1 / 4)) * 4;
    const u16* hr = h + s * TWO_FFN;
    uint2 gv = *(const uint2*)(hr + f);
    uint2 uv = *(const uint2*)(hr + FFN1 + f);
    float g0 = bf2f((u16)(gv.x & 0xFFFF)), g1 = bf2f((u16)(gv.x >> 16));
    float g2 = bf2f((u16)(gv.y & 0xFFFF)), g3 = bf2f((u16)(gv.y >> 16));
    float u0 = bf2f((u16)(uv.x & 0xFFFF)), u1 = bf2f((u16)(uv.x >> 16));
    float u2 = bf2f((u16)(uv.y & 0xFFFF)), u3 = bf2f((u16)(uv.y >> 16));
    float a0 = g0 / (1.f + expf(-g0)) * u0;
    float a1 = g1 / (1.f + expf(-g1)) * u1;
    float a2 = g2 / (1.f + expf(-g2)) * u2;
    float a3 = g3 / (1.f + expf(-g3)) * u3;
    uint2 o;
    o.x = pack2(a0, a1);
    o.y = pack2(a2, a3);
    *(uint2*)(act + s * FFN1 + f) = o;
}

// ---------------- combine: out[t] = w0*y[slot0] + w1*y[slot1] ----------------
__global__ __launch_bounds__(256) void combine_kernel(
    const u16* __restrict__ y, const int* __restrict__ inv,
    const float2* __restrict__ wts, float* __restrict__ out) {
    int t = blockIdx.x >> 1;
    int c = ((blockIdx.x & 1) << 10) + threadIdx.x * 4;
    int s0 = inv[2 * t], s1 = inv[2 * t + 1];
    float2 w = wts[t];
    uint2 a = *(const uint2*)(y + (long)s0 * HID + c);
    uint2 b = *(const uint2*)(y + (long)s1 * HID + c);
    float4 o;
    o.x = w.x * bf2f((u16)(a.x & 0xFFFF)) + w.y * bf2f((u16)(b.x & 0xFFFF));
    o.y = w.x * bf2f((u16)(a.x >> 16))   + w.y * bf2f((u16)(b.x >> 16));
    o.z = w.x * bf2f((u16)(a.y & 0xFFFF)) + w.y * bf2f((u16)(b.y & 0xFFFF));
    o.w = w.x * bf2f((u16)(a.y >> 16))   + w.y * bf2f((u16)(b.y >> 16));
    *(float4*)(out + (long)t * HID + c) = o;
}

extern "C" void kernel_launch(void* const* d_in, const int* in_sizes, int n_in,
                              void* d_out, int out_size, void* d_ws, size_t ws_size,
                              hipStream_t stream) {
    const float* hidden = (const float*)d_in[0];   // [4096, 2048]
    const float* gate_w = (const float*)d_in[1];   // [2048, 8]
    const float* w1     = (const float*)d_in[2];   // [8, 2816, 2048]
    const float* w2     = (const float*)d_in[3];   // [8, 2048, 1408]
    float* out_final  = (float*)d_out;                       // [4096, 2048]
    float* out_logits = out_final + (long)T_SEQ * HID;       // [4096, 8]

    const long W1N = (long)NE * TWO_FFN * HID;   // 46,137,344 elems
    const long W2N = (long)NE * HID * FFN1;      // 23,068,672
    const long ABN = (long)NSLOT * HID;          // 16,777,216
    const long HN  = (long)NSLOT * TWO_FFN;      // 23,068,672

    u16* w1b = (u16*)d_ws;
    u16* w2b = w1b + W1N;
    u16* Ab  = w2b + W2N;
    u16* h   = Ab + ABN;
    int* counts = (int*)(h + HN);
    int* cursor = counts + 8;
    int* offs   = counts + 16;    // 9 ints (padded region)
    int* pairs  = counts + 32;
    float2* wts = (float2*)(pairs + T_SEQ);
    int* tok_of = (int*)(wts + T_SEQ);
    int* inv    = tok_of + NSLOT;
    u16* act = w1b;   // alias: w1b dead after GEMM1
    u16* yb  = Ab;    // alias: Ab dead after GEMM1

    hipMemsetAsync(counts, 0, 64, stream);   // counts[8] + cursor[8]
    router_kernel<<<T_SEQ / 4, 256, 0, stream>>>(hidden, gate_w, out_logits, pairs, wts, counts);
    offsets_kernel<<<1, 1, 0, stream>>>(counts, offs);
    scatter_kernel<<<T_SEQ / 256, 256, 0, stream>>>(pairs, offs, cursor, tok_of, inv);
    gather_kernel<<<NSLOT, 256, 0, stream>>>(hidden, tok_of, Ab);
    cvt_kernel<<<(int)(W1N / 2048), 256, 0, stream>>>(w1, w1b, W1N);
    cvt_kernel<<<(int)(W2N / 2048), 256, 0, stream>>>(w2, w2b, W2N);
    gemm_bt<<<dim3(32, TWO_FFN / 128, NE), 256, 0, stream>>>(Ab, w1b, h, offs, TWO_FFN, HID, TWO_FFN, NSLOT);
    act_kernel<<<(int)((long)NSLOT * FFN1 / 4 / 256), 256, 0, stream>>>(h, act);
    gemm_bt<<<dim3(32, HID / 128, NE), 256, 0, stream>>>(act, w2b, yb, offs, HID, FFN1, HID, NSLOT);
    combine_kernel<<<NSLOT, 256, 0, stream>>>(yb, inv, wts, out_final);
}

// Round 2
// 793.497 us; speedup vs baseline: 1.5456x; 1.5456x over previous
//
#include <hip/hip_runtime.h>
#include <math.h>

#define T_SEQ 4096
#define HID 2048
#define FFN1 1408
#define TWO_FFN 2816
#define NE 8
#define NSLOT 8192   // T_SEQ * TOP_K
#define MAXT 72      // max live m-tiles: 8192/128 + 8

typedef unsigned short u16;
typedef __bf16 bf16x8_t __attribute__((ext_vector_type(8)));
typedef float f32x4_t __attribute__((ext_vector_type(4)));

__device__ __forceinline__ u16 f2bf(float f) {
    union { float f; unsigned int u; } v; v.f = f;
    unsigned int u = v.u;
    unsigned int r = u + 0x7FFFu + ((u >> 16) & 1u);
    return (u16)(r >> 16);
}
__device__ __forceinline__ float bf2f(u16 b) {
    union { unsigned int u; float f; } v; v.u = ((unsigned int)b) << 16;
    return v.f;
}
__device__ __forceinline__ unsigned pack2(float a, float b) {
    return (unsigned)f2bf(a) | ((unsigned)f2bf(b) << 16);
}

// ---------------- fp32 -> bf16 bulk convert (8 elems/thread) ----------------
__global__ __launch_bounds__(256) void cvt_kernel(const float* __restrict__ in,
                                                  u16* __restrict__ out, long n) {
    long i = ((long)blockIdx.x * 256 + threadIdx.x) * 8;
    if (i + 8 > n) return;
    const float4* p = (const float4*)(in + i);
    float4 a = p[0], b = p[1];
    uint4 o;
    o.x = pack2(a.x, a.y);
    o.y = pack2(a.z, a.w);
    o.z = pack2(b.x, b.y);
    o.w = pack2(b.z, b.w);
    *(uint4*)(out + i) = o;
}

// ---------------- router: logits, top-2, weights, counts ----------------
__global__ __launch_bounds__(256) void router_kernel(
    const float* __restrict__ x, const float* __restrict__ gw,
    float* __restrict__ logits_out, int* __restrict__ pairs,
    float2* __restrict__ wts, int* __restrict__ counts) {
    int wave = threadIdx.x >> 6, lane = threadIdx.x & 63;
    int t = blockIdx.x * 4 + wave;
    float acc[NE] = {0.f,0.f,0.f,0.f,0.f,0.f,0.f,0.f};
    const float* xr = x + (long)t * HID;
    for (int i = 0; i < HID / 64; ++i) {
        int hh = i * 64 + lane;
        float xv = xr[hh];
        const float4* g4 = (const float4*)(gw + (long)hh * NE);
        float4 g0 = g4[0], g1 = g4[1];
        acc[0] += xv * g0.x; acc[1] += xv * g0.y;
        acc[2] += xv * g0.z; acc[3] += xv * g0.w;
        acc[4] += xv * g1.x; acc[5] += xv * g1.y;
        acc[6] += xv * g1.z; acc[7] += xv * g1.w;
    }
    #pragma unroll
    for (int m = 1; m < 64; m <<= 1) {
        #pragma unroll
        for (int e = 0; e < NE; ++e) acc[e] += __shfl_xor(acc[e], m, 64);
    }
    if (lane == 0) {
        float* lo = logits_out + (long)t * NE;
        #pragma unroll
        for (int e = 0; e < NE; ++e) lo[e] = acc[e];
        int a = 0; float va = acc[0];
        #pragma unroll
        for (int e = 1; e < NE; ++e) if (acc[e] > va) { va = acc[e]; a = e; }
        int b = -1; float vb = 0.f;
        #pragma unroll
        for (int e = 0; e < NE; ++e) {
            if (e == a) continue;
            if (b < 0 || acc[e] > vb) { vb = acc[e]; b = e; }
        }
        float w0 = 1.0f / (1.0f + expf(vb - va));
        pairs[t] = a | (b << 8);
        wts[t] = make_float2(w0, 1.0f - w0);
        atomicAdd(counts + a, 1);
        atomicAdd(counts + b, 1);
    }
}

// ---------------- prefix offsets + live-tile table (E=8, single thread) -----
__global__ void offsets_kernel(const int* __restrict__ counts, int* __restrict__ offs,
                               int* __restrict__ tiles) {
    int s = 0;
    for (int e = 0; e < NE; ++e) { offs[e] = s; s += counts[e]; }
    offs[NE] = s;
    int nt = 0;
    for (int e = 0; e < NE; ++e)
        for (int m0 = 0; m0 < counts[e]; m0 += 128)
            tiles[nt++] = (e << 20) | m0;
    for (; nt < MAXT; ++nt) tiles[nt] = -1;
}

// ---------------- scatter tokens into compact expert segments ----------------
__global__ __launch_bounds__(256) void scatter_kernel(
    const int* __restrict__ pairs, const int* __restrict__ offs,
    int* __restrict__ cursor, int* __restrict__ tok_of, int* __restrict__ inv) {
    int t = blockIdx.x * 256 + threadIdx.x;
    if (t >= T_SEQ) return;
    int pr = pairs[t];
    int a = pr & 0xFF, b = (pr >> 8) & 0xFF;
    int p0 = atomicAdd(cursor + a, 1);
    int s0 = offs[a] + p0;
    tok_of[s0] = t; inv[2 * t] = s0;
    int p1 = atomicAdd(cursor + b, 1);
    int s1 = offs[b] + p1;
    tok_of[s1] = t; inv[2 * t + 1] = s1;
}

// ---------------- gather hidden rows to compact bf16 A ----------------
__global__ __launch_bounds__(256) void gather_kernel(
    const float* __restrict__ x, const int* __restrict__ tok_of, u16* __restrict__ Ab) {
    int slot = blockIdx.x;
    int tok = tok_of[slot];
    int c = threadIdx.x * 8;
    const float4* p = (const float4*)(x + (long)tok * HID + c);
    float4 a = p[0], b = p[1];
    uint4 o;
    o.x = pack2(a.x, a.y);
    o.y = pack2(a.z, a.w);
    o.z = pack2(b.x, b.y);
    o.w = pack2(b.z, b.w);
    *(uint4*)(Ab + (long)slot * HID + c) = o;
}

// ---------------- grouped GEMM: dbuf LDS + async prefetch ----------------
// A [NSLOT, K] bf16 row-major (compact slots); B [E, N, K] bf16 (B^T layout);
// C [NSLOT, ldc] bf16. Live m-tiles enumerated by tiles[] table.
__device__ __forceinline__ void async16(const u16* g, u16* l) {
    __builtin_amdgcn_global_load_lds(
        (const __attribute__((address_space(1))) void*)g,
        (__attribute__((address_space(3))) void*)l, 16, 0, 0);
}

__global__ __launch_bounds__(256) void gemm_bt(
    const u16* __restrict__ A, const u16* __restrict__ B, u16* __restrict__ C,
    const int* __restrict__ offs, const int* __restrict__ tiles,
    int N, int K, int ldc, int Mtot) {
    int ent = tiles[blockIdx.x];
    if (ent < 0) return;
    int e = ent >> 20;
    int m0 = ent & 0xFFFFF;
    int m_base = offs[e];
    int m_cnt = offs[e + 1] - m_base;
    int n0 = blockIdx.y * 128;

    // double-buffered tiles: 2 x (128 rows x 32 cols) bf16 = 2 x 8KB each
    __shared__ u16 As[2 * 128 * 32];
    __shared__ u16 Bs[2 * 128 * 32];

    int tid = threadIdx.x;
    int lane = tid & 63;
    int wave = tid >> 6;
    const u16* Be = B + (long)e * N * K;

    int rA0 = m_base + m0 + (tid >> 2);
    int rA1 = rA0 + 64;
    if (rA0 > Mtot - 1) rA0 = Mtot - 1;   // clamp: garbage rows masked at store
    if (rA1 > Mtot - 1) rA1 = Mtot - 1;
    int ch = (tid & 3) * 8;
    const u16* gA0 = A + (long)rA0 * K + ch;
    const u16* gA1 = A + (long)rA1 * K + ch;
    const u16* gB0 = Be + (long)(n0 + (tid >> 2)) * K + ch;
    const u16* gB1 = Be + (long)(n0 + 64 + (tid >> 2)) * K + ch;

    f32x4_t acc[4][4] = {};
    int wm = (wave >> 1) << 6;
    int wn = (wave & 1) << 6;
    int fr = lane & 15;
    int kg = (lane >> 4) * 8;

    // preamble: stage tile k0=0 into buffer 0
    async16(gA0, As + tid * 8);
    async16(gA1, As + (256 + tid) * 8);
    async16(gB0, Bs + tid * 8);
    async16(gB1, Bs + (256 + tid) * 8);

    int p = 0;
    for (int k0 = 0; k0 < K; k0 += 32) {
        __syncthreads();   // implicit vmcnt(0): buf p ready; buf 1-p reads done
        int kn = k0 + 32;
        if (kn < K) {
            int q = p ^ 1;
            async16(gA0 + kn, As + q * 4096 + tid * 8);
            async16(gA1 + kn, As + q * 4096 + (256 + tid) * 8);
            async16(gB0 + kn, Bs + q * 4096 + tid * 8);
            async16(gB1 + kn, Bs + q * 4096 + (256 + tid) * 8);
        }
        const u16* Ap = As + p * 4096;
        const u16* Bp = Bs + p * 4096;
        bf16x8_t av[4], bv[4];
        #pragma unroll
        for (int i = 0; i < 4; ++i)
            av[i] = *(const bf16x8_t*)(Ap + (wm + i * 16 + fr) * 32 + kg);
        #pragma unroll
        for (int j = 0; j < 4; ++j)
            bv[j] = *(const bf16x8_t*)(Bp + (wn + j * 16 + fr) * 32 + kg);
        #pragma unroll
        for (int i = 0; i < 4; ++i)
            #pragma unroll
            for (int j = 0; j < 4; ++j)
                acc[i][j] = __builtin_amdgcn_mfma_f32_16x16x32_bf16(av[i], bv[j], acc[i][j], 0, 0, 0);
        p ^= 1;
    }

    // epilogue: C/D layout col=lane&15, row=(lane>>4)*4+reg  [m89-verified]
    int cr = (lane >> 4) * 4;
    int cc = lane & 15;
    #pragma unroll
    for (int i = 0; i < 4; ++i) {
        #pragma unroll
        for (int j = 0; j < 4; ++j) {
            int gcol = n0 + wn + j * 16 + cc;
            #pragma unroll
            for (int r = 0; r < 4; ++r) {
                int mr = m0 + wm + i * 16 + cr + r;
                if (mr < m_cnt)
                    C[(long)(m_base + mr) * ldc + gcol] = f2bf(acc[i][j][r]);
            }
        }
    }
}

// ---------------- SiLU gate: act = silu(g) * u ----------------
__global__ __launch_bounds__(256) void act_kernel(const u16* __restrict__ h,
                                                  u16* __restrict__ act) {
    long i = (long)blockIdx.x * 256 + threadIdx.x;   // one per 4 elems
    long s = i / (FFN1 / 4);
    int f = (int)(i % (FFN1 / 4)) * 4;
    const u16* hr = h + s * TWO_FFN;
    uint2 gv = *(const uint2*)(hr + f);
    uint2 uv = *(const uint2*)(hr + FFN1 + f);
    float g0 = bf2f((u16)(gv.x & 0xFFFF)), g1 = bf2f((u16)(gv.x >> 16));
    float g2 = bf2f((u16)(gv.y & 0xFFFF)), g3 = bf2f((u16)(gv.y >> 16));
    float u0 = bf2f((u16)(uv.x & 0xFFFF)), u1 = bf2f((u16)(uv.x >> 16));
    float u2 = bf2f((u16)(uv.y & 0xFFFF)), u3 = bf2f((u16)(uv.y >> 16));
    float a0 = g0 / (1.f + expf(-g0)) * u0;
    float a1 = g1 / (1.f + expf(-g1)) * u1;
    float a2 = g2 / (1.f + expf(-g2)) * u2;
    float a3 = g3 / (1.f + expf(-g3)) * u3;
    uint2 o;
    o.x = pack2(a0, a1);
    o.y = pack2(a2, a3);
    *(uint2*)(act + s * FFN1 + f) = o;
}

// ---------------- combine: out[t] = w0*y[slot0] + w1*y[slot1] ----------------
__global__ __launch_bounds__(256) void combine_kernel(
    const u16* __restrict__ y, const int* __restrict__ inv,
    const float2* __restrict__ wts, float* __restrict__ out) {
    int t = blockIdx.x >> 1;
    int c = ((blockIdx.x & 1) << 10) + threadIdx.x * 4;
    int s0 = inv[2 * t], s1 = inv[2 * t + 1];
    float2 w = wts[t];
    uint2 a = *(const uint2*)(y + (long)s0 * HID + c);
    uint2 b = *(const uint2*)(y + (long)s1 * HID + c);
    float4 o;
    o.x = w.x * bf2f((u16)(a.x & 0xFFFF)) + w.y * bf2f((u16)(b.x & 0xFFFF));
    o.y = w.x * bf2f((u16)(a.x >> 16))   + w.y * bf2f((u16)(b.x >> 16));
    o.z = w.x * bf2f((u16)(a.y & 0xFFFF)) + w.y * bf2f((u16)(b.y & 0xFFFF));
    o.w = w.x * bf2f((u16)(a.y >> 16))   + w.y * bf2f((u16)(b.y >> 16));
    *(float4*)(out + (long)t * HID + c) = o;
}

extern "C" void kernel_launch(void* const* d_in, const int* in_sizes, int n_in,
                              void* d_out, int out_size, void* d_ws, size_t ws_size,
                              hipStream_t stream) {
    const float* hidden = (const float*)d_in[0];   // [4096, 2048]
    const float* gate_w = (const float*)d_in[1];   // [2048, 8]
    const float* w1     = (const float*)d_in[2];   // [8, 2816, 2048]
    const float* w2     = (const float*)d_in[3];   // [8, 2048, 1408]
    float* out_final  = (float*)d_out;                       // [4096, 2048]
    float* out_logits = out_final + (long)T_SEQ * HID;       // [4096, 8]

    const long W1N = (long)NE * TWO_FFN * HID;   // 46,137,344 elems
    const long W2N = (long)NE * HID * FFN1;      // 23,068,672
    const long ABN = (long)NSLOT * HID;          // 16,777,216
    const long HN  = (long)NSLOT * TWO_FFN;      // 23,068,672

    u16* w1b = (u16*)d_ws;
    u16* w2b = w1b + W1N;
    u16* Ab  = w2b + W2N;
    u16* h   = Ab + ABN;
    int* counts = (int*)(h + HN);
    int* cursor = counts + 8;
    int* offs   = counts + 16;    // 9 ints (padded region)
    int* pairs  = counts + 32;
    float2* wts = (float2*)(pairs + T_SEQ);
    int* tok_of = (int*)(wts + T_SEQ);
    int* inv    = tok_of + NSLOT;
    int* tiles  = inv + 2 * T_SEQ;   // MAXT ints
    u16* act = w1b;   // alias: w1b dead after GEMM1
    u16* yb  = Ab;    // alias: Ab dead after GEMM1

    hipMemsetAsync(counts, 0, 64, stream);   // counts[8] + cursor[8]
    router_kernel<<<T_SEQ / 4, 256, 0, stream>>>(hidden, gate_w, out_logits, pairs, wts, counts);
    offsets_kernel<<<1, 1, 0, stream>>>(counts, offs, tiles);
    scatter_kernel<<<T_SEQ / 256, 256, 0, stream>>>(pairs, offs, cursor, tok_of, inv);
    gather_kernel<<<NSLOT, 256, 0, stream>>>(hidden, tok_of, Ab);
    cvt_kernel<<<(int)(W1N / 2048), 256, 0, stream>>>(w1, w1b, W1N);
    cvt_kernel<<<(int)(W2N / 2048), 256, 0, stream>>>(w2, w2b, W2N);
    gemm_bt<<<dim3(MAXT, TWO_FFN / 128), 256, 0, stream>>>(Ab, w1b, h, offs, tiles, TWO_FFN, HID, TWO_FFN, NSLOT);
    act_kernel<<<(int)((long)NSLOT * FFN1 / 4 / 256), 256, 0, stream>>>(h, act);
    gemm_bt<<<dim3(MAXT, HID / 128), 256, 0, stream>>>(act, w2b, yb, offs, tiles, HID, FFN1, HID, NSLOT);
    combine_kernel<<<NSLOT, 256, 0, stream>>>(yb, inv, wts, out_final);
}

// Round 3
// 783.983 us; speedup vs baseline: 1.5643x; 1.0121x over previous
//
#include <hip/hip_runtime.h>
#include <math.h>

#define T_SEQ 4096
#define HID 2048
#define FFN1 1408
#define TWO_FFN 2816
#define NE 8
#define NSLOT 8192   // T_SEQ * TOP_K
#define MAXT 72      // max live m-tiles: 8192/128 + 8

typedef unsigned short u16;
typedef __bf16 bf16x8_t __attribute__((ext_vector_type(8)));
typedef float f32x4_t __attribute__((ext_vector_type(4)));

__device__ __forceinline__ u16 f2bf(float f) {
    union { float f; unsigned int u; } v; v.f = f;
    unsigned int u = v.u;
    unsigned int r = u + 0x7FFFu + ((u >> 16) & 1u);
    return (u16)(r >> 16);
}
__device__ __forceinline__ float bf2f(u16 b) {
    union { unsigned int u; float f; } v; v.u = ((unsigned int)b) << 16;
    return v.f;
}
__device__ __forceinline__ unsigned pack2(float a, float b) {
    return (unsigned)f2bf(a) | ((unsigned)f2bf(b) << 16);
}

// ---------------- fp32 -> bf16 bulk convert (8 elems/thread) ----------------
__global__ __launch_bounds__(256) void cvt_kernel(const float* __restrict__ in,
                                                  u16* __restrict__ out, long n) {
    long i = ((long)blockIdx.x * 256 + threadIdx.x) * 8;
    if (i + 8 > n) return;
    const float4* p = (const float4*)(in + i);
    float4 a = p[0], b = p[1];
    uint4 o;
    o.x = pack2(a.x, a.y);
    o.y = pack2(a.z, a.w);
    o.z = pack2(b.x, b.y);
    o.w = pack2(b.z, b.w);
    *(uint4*)(out + i) = o;
}

// ---------------- router: logits, top-2, weights, counts ----------------
__global__ __launch_bounds__(256) void router_kernel(
    const float* __restrict__ x, const float* __restrict__ gw,
    float* __restrict__ logits_out, int* __restrict__ pairs,
    float2* __restrict__ wts, int* __restrict__ counts) {
    int wave = threadIdx.x >> 6, lane = threadIdx.x & 63;
    int t = blockIdx.x * 4 + wave;
    float acc[NE] = {0.f,0.f,0.f,0.f,0.f,0.f,0.f,0.f};
    const float* xr = x + (long)t * HID;
    for (int i = 0; i < HID / 64; ++i) {
        int hh = i * 64 + lane;
        float xv = xr[hh];
        const float4* g4 = (const float4*)(gw + (long)hh * NE);
        float4 g0 = g4[0], g1 = g4[1];
        acc[0] += xv * g0.x; acc[1] += xv * g0.y;
        acc[2] += xv * g0.z; acc[3] += xv * g0.w;
        acc[4] += xv * g1.x; acc[5] += xv * g1.y;
        acc[6] += xv * g1.z; acc[7] += xv * g1.w;
    }
    #pragma unroll
    for (int m = 1; m < 64; m <<= 1) {
        #pragma unroll
        for (int e = 0; e < NE; ++e) acc[e] += __shfl_xor(acc[e], m, 64);
    }
    if (lane == 0) {
        float* lo = logits_out + (long)t * NE;
        #pragma unroll
        for (int e = 0; e < NE; ++e) lo[e] = acc[e];
        int a = 0; float va = acc[0];
        #pragma unroll
        for (int e = 1; e < NE; ++e) if (acc[e] > va) { va = acc[e]; a = e; }
        int b = -1; float vb = 0.f;
        #pragma unroll
        for (int e = 0; e < NE; ++e) {
            if (e == a) continue;
            if (b < 0 || acc[e] > vb) { vb = acc[e]; b = e; }
        }
        float w0 = 1.0f / (1.0f + expf(vb - va));
        pairs[t] = a | (b << 8);
        wts[t] = make_float2(w0, 1.0f - w0);
        atomicAdd(counts + a, 1);
        atomicAdd(counts + b, 1);
    }
}

// ------- prefix offsets + live-tile table (one wave, shfl scans) -------
__global__ void offsets_kernel(const int* __restrict__ counts, int* __restrict__ offs,
                               int* __restrict__ tiles) {
    int lane = threadIdx.x;   // 64 threads
    int c = (lane < NE) ? counts[lane] : 0;
    int s = c;
    #pragma unroll
    for (int m = 1; m < NE; m <<= 1) {
        int t = __shfl_up(s, m, 64);
        if (lane >= m) s += t;
    }
    if (lane < NE) offs[lane] = s - c;
    if (lane == NE - 1) offs[NE] = s;
    int nt = (lane < NE) ? ((c + 127) >> 7) : 0;
    int ts = nt;
    #pragma unroll
    for (int m = 1; m < NE; m <<= 1) {
        int t = __shfl_up(ts, m, 64);
        if (lane >= m) ts += t;
    }
    int tbase = ts - nt;
    if (lane < NE)
        for (int i = 0; i < nt; ++i) tiles[tbase + i] = (lane << 20) | (i << 7);
    int nt_tot = __shfl(ts, NE - 1, 64);
    for (int j = lane; j < MAXT; j += 64)
        if (j >= nt_tot) tiles[j] = -1;
}

// ---------------- scatter tokens into compact expert segments ----------------
__global__ __launch_bounds__(256) void scatter_kernel(
    const int* __restrict__ pairs, const int* __restrict__ offs,
    int* __restrict__ cursor, int* __restrict__ tok_of, int* __restrict__ inv) {
    int t = blockIdx.x * 256 + threadIdx.x;
    if (t >= T_SEQ) return;
    int pr = pairs[t];
    int a = pr & 0xFF, b = (pr >> 8) & 0xFF;
    int p0 = atomicAdd(cursor + a, 1);
    int s0 = offs[a] + p0;
    tok_of[s0] = t; inv[2 * t] = s0;
    int p1 = atomicAdd(cursor + b, 1);
    int s1 = offs[b] + p1;
    tok_of[s1] = t; inv[2 * t + 1] = s1;
}

// ---------------- gather hidden rows to compact bf16 A ----------------
__global__ __launch_bounds__(256) void gather_kernel(
    const float* __restrict__ x, const int* __restrict__ tok_of, u16* __restrict__ Ab) {
    int slot = blockIdx.x;
    int tok = tok_of[slot];
    int c = threadIdx.x * 8;
    const float4* p = (const float4*)(x + (long)tok * HID + c);
    float4 a = p[0], b = p[1];
    uint4 o;
    o.x = pack2(a.x, a.y);
    o.y = pack2(a.z, a.w);
    o.z = pack2(b.x, b.y);
    o.w = pack2(b.z, b.w);
    *(uint4*)(Ab + (long)slot * HID + c) = o;
}

// ---------------- grouped GEMM: dbuf LDS + async prefetch + XOR swizzle -----
// A [NSLOT, K] bf16 row-major (compact slots); B [E, N, K] bf16 (B^T layout);
// C [NSLOT, ldc] bf16. Live m-tiles enumerated by tiles[] table.
// LDS layout: chunk (16B) of row r, k-group c stored at position c ^ ((r>>1)&3)
// -> consecutive lanes of a ds_read_b128 cover all 8 bank quads (conflict-free).
__device__ __forceinline__ void async16(const u16* g, u16* l) {
    __builtin_amdgcn_global_load_lds(
        (const __attribute__((address_space(1))) void*)g,
        (__attribute__((address_space(3))) void*)l, 16, 0, 0);
}

__global__ __launch_bounds__(256) void gemm_bt(
    const u16* __restrict__ A, const u16* __restrict__ B, u16* __restrict__ C,
    const int* __restrict__ offs, const int* __restrict__ tiles,
    int N, int K, int ldc, int Mtot) {
    int ent = tiles[blockIdx.x];
    if (ent < 0) return;
    int e = ent >> 20;
    int m0 = ent & 0xFFFFF;
    int m_base = offs[e];
    int m_cnt = offs[e + 1] - m_base;
    int n0 = blockIdx.y * 128;

    // double-buffered tiles: 2 x (128 rows x 32 cols) bf16 = 2 x 8KB each
    __shared__ u16 As[2 * 128 * 32];
    __shared__ u16 Bs[2 * 128 * 32];

    int tid = threadIdx.x;
    int lane = tid & 63;
    int wave = tid >> 6;
    const u16* Be = B + (long)e * N * K;

    int rA0 = m_base + m0 + (tid >> 2);
    int rA1 = rA0 + 64;
    if (rA0 > Mtot - 1) rA0 = Mtot - 1;   // clamp: garbage rows masked at store
    if (rA1 > Mtot - 1) rA1 = Mtot - 1;
    // staging chunk: pos = tid&3 holds global chunk (tid&3) ^ ((row>>1)&3)
    int ch = ((tid & 3) ^ ((tid >> 3) & 3)) * 8;
    const u16* gA0 = A + (long)rA0 * K + ch;
    const u16* gA1 = A + (long)rA1 * K + ch;
    const u16* gB0 = Be + (long)(n0 + (tid >> 2)) * K + ch;
    const u16* gB1 = Be + (long)(n0 + 64 + (tid >> 2)) * K + ch;

    f32x4_t acc[4][4] = {};
    int wm = (wave >> 1) << 6;
    int wn = (wave & 1) << 6;
    int fr = lane & 15;
    // read k-group c = lane>>4 of row (..+fr): position (lane>>4) ^ ((fr>>1)&3)
    int kg = ((lane >> 4) ^ ((lane >> 1) & 3)) * 8;

    // preamble: stage tile k0=0 into buffer 0
    async16(gA0, As + tid * 8);
    async16(gA1, As + (256 + tid) * 8);
    async16(gB0, Bs + tid * 8);
    async16(gB1, Bs + (256 + tid) * 8);

    int p = 0;
    for (int k0 = 0; k0 < K; k0 += 32) {
        __syncthreads();   // implicit vmcnt(0): buf p ready; buf 1-p reads done
        int kn = k0 + 32;
        if (kn < K) {
            int q = p ^ 1;
            async16(gA0 + kn, As + q * 4096 + tid * 8);
            async16(gA1 + kn, As + q * 4096 + (256 + tid) * 8);
            async16(gB0 + kn, Bs + q * 4096 + tid * 8);
            async16(gB1 + kn, Bs + q * 4096 + (256 + tid) * 8);
        }
        const u16* Ap = As + p * 4096;
        const u16* Bp = Bs + p * 4096;
        bf16x8_t av[4], bv[4];
        #pragma unroll
        for (int i = 0; i < 4; ++i)
            av[i] = *(const bf16x8_t*)(Ap + (wm + i * 16 + fr) * 32 + kg);
        #pragma unroll
        for (int j = 0; j < 4; ++j)
            bv[j] = *(const bf16x8_t*)(Bp + (wn + j * 16 + fr) * 32 + kg);
        #pragma unroll
        for (int i = 0; i < 4; ++i)
            #pragma unroll
            for (int j = 0; j < 4; ++j)
                acc[i][j] = __builtin_amdgcn_mfma_f32_16x16x32_bf16(av[i], bv[j], acc[i][j], 0, 0, 0);
        p ^= 1;
    }

    // epilogue: C/D layout col=lane&15, row=(lane>>4)*4+reg  [m89-verified]
    int cr = (lane >> 4) * 4;
    int cc = lane & 15;
    #pragma unroll
    for (int i = 0; i < 4; ++i) {
        #pragma unroll
        for (int j = 0; j < 4; ++j) {
            int gcol = n0 + wn + j * 16 + cc;
            #pragma unroll
            for (int r = 0; r < 4; ++r) {
                int mr = m0 + wm + i * 16 + cr + r;
                if (mr < m_cnt)
                    C[(long)(m_base + mr) * ldc + gcol] = f2bf(acc[i][j][r]);
            }
        }
    }
}

// ---------------- SiLU gate: act = silu(g) * u ----------------
__global__ __launch_bounds__(256) void act_kernel(const u16* __restrict__ h,
                                                  u16* __restrict__ act) {
    long i = (long)blockIdx.x * 256 + threadIdx.x;   // one per 4 elems
    long s = i / (FFN1 / 4);
    int f = (int)(i % (FFN1 / 4)) * 4;
    const u16* hr = h + s * TWO_FFN;
    uint2 gv = *(const uint2*)(hr + f);
    uint2 uv = *(const uint2*)(hr + FFN1 + f);
    float g0 = bf2f((u16)(gv.x & 0xFFFF)), g1 = bf2f((u16)(gv.x >> 16));
    float g2 = bf2f((u16)(gv.y & 0xFFFF)), g3 = bf2f((u16)(gv.y >> 16));
    float u0 = bf2f((u16)(uv.x & 0xFFFF)), u1 = bf2f((u16)(uv.x >> 16));
    float u2 = bf2f((u16)(uv.y & 0xFFFF)), u3 = bf2f((u16)(uv.y >> 16));
    float a0 = g0 / (1.f + expf(-g0)) * u0;
    float a1 = g1 / (1.f + expf(-g1)) * u1;
    float a2 = g2 / (1.f + expf(-g2)) * u2;
    float a3 = g3 / (1.f + expf(-g3)) * u3;
    uint2 o;
    o.x = pack2(a0, a1);
    o.y = pack2(a2, a3);
    *(uint2*)(act + s * FFN1 + f) = o;
}

// ---------------- combine: out[t] = w0*y[slot0] + w1*y[slot1] ----------------
__global__ __launch_bounds__(256) void combine_kernel(
    const u16* __restrict__ y, const int* __restrict__ inv,
    const float2* __restrict__ wts, float* __restrict__ out) {
    int t = blockIdx.x >> 1;
    int c = ((blockIdx.x & 1) << 10) + threadIdx.x * 4;
    int s0 = inv[2 * t], s1 = inv[2 * t + 1];
    float2 w = wts[t];
    uint2 a = *(const uint2*)(y + (long)s0 * HID + c);
    uint2 b = *(const uint2*)(y + (long)s1 * HID + c);
    float4 o;
    o.x = w.x * bf2f((u16)(a.x & 0xFFFF)) + w.y * bf2f((u16)(b.x & 0xFFFF));
    o.y = w.x * bf2f((u16)(a.x >> 16))   + w.y * bf2f((u16)(b.x >> 16));
    o.z = w.x * bf2f((u16)(a.y & 0xFFFF)) + w.y * bf2f((u16)(b.y & 0xFFFF));
    o.w = w.x * bf2f((u16)(a.y >> 16))   + w.y * bf2f((u16)(b.y >> 16));
    *(float4*)(out + (long)t * HID + c) = o;
}

extern "C" void kernel_launch(void* const* d_in, const int* in_sizes, int n_in,
                              void* d_out, int out_size, void* d_ws, size_t ws_size,
                              hipStream_t stream) {
    const float* hidden = (const float*)d_in[0];   // [4096, 2048]
    const float* gate_w = (const float*)d_in[1];   // [2048, 8]
    const float* w1     = (const float*)d_in[2];   // [8, 2816, 2048]
    const float* w2     = (const float*)d_in[3];   // [8, 2048, 1408]
    float* out_final  = (float*)d_out;                       // [4096, 2048]
    float* out_logits = out_final + (long)T_SEQ * HID;       // [4096, 8]

    const long W1N = (long)NE * TWO_FFN * HID;   // 46,137,344 elems
    const long W2N = (long)NE * HID * FFN1;      // 23,068,672
    const long ABN = (long)NSLOT * HID;          // 16,777,216
    const long HN  = (long)NSLOT * TWO_FFN;      // 23,068,672

    u16* w1b = (u16*)d_ws;
    u16* w2b = w1b + W1N;
    u16* Ab  = w2b + W2N;
    u16* h   = Ab + ABN;
    int* counts = (int*)(h + HN);
    int* cursor = counts + 8;
    int* offs   = counts + 16;    // 9 ints (padded region)
    int* pairs  = counts + 32;
    float2* wts = (float2*)(pairs + T_SEQ);
    int* tok_of = (int*)(wts + T_SEQ);
    int* inv    = tok_of + NSLOT;
    int* tiles  = inv + 2 * T_SEQ;   // MAXT ints
    u16* act = w1b;   // alias: w1b dead after GEMM1
    u16* yb  = Ab;    // alias: Ab dead after GEMM1

    hipMemsetAsync(counts, 0, 64, stream);   // counts[8] + cursor[8]
    router_kernel<<<T_SEQ / 4, 256, 0, stream>>>(hidden, gate_w, out_logits, pairs, wts, counts);
    offsets_kernel<<<1, 64, 0, stream>>>(counts, offs, tiles);
    scatter_kernel<<<T_SEQ / 256, 256, 0, stream>>>(pairs, offs, cursor, tok_of, inv);
    gather_kernel<<<NSLOT, 256, 0, stream>>>(hidden, tok_of, Ab);
    cvt_kernel<<<(int)(W1N / 2048), 256, 0, stream>>>(w1, w1b, W1N);
    cvt_kernel<<<(int)(W2N / 2048), 256, 0, stream>>>(w2, w2b, W2N);
    gemm_bt<<<dim3(MAXT, TWO_FFN / 128), 256, 0, stream>>>(Ab, w1b, h, offs, tiles, TWO_FFN, HID, TWO_FFN, NSLOT);
    act_kernel<<<(int)((long)NSLOT * FFN1 / 4 / 256), 256, 0, stream>>>(h, act);
    gemm_bt<<<dim3(MAXT, HID / 128), 256, 0, stream>>>(act, w2b, yb, offs, tiles, HID, FFN1, HID, NSLOT);
    combine_kernel<<<NSLOT, 256, 0, stream>>>(yb, inv, wts, out_final);
}